// Round 2
// baseline (109.804 us; speedup 1.0000x reference)
//
#include <hip/hip_runtime.h>
#include <hip/hip_bf16.h>

typedef unsigned short u16;
typedef __bf16 bf16x8 __attribute__((ext_vector_type(8)));
typedef __bf16 bf16x4 __attribute__((ext_vector_type(4)));
typedef float f32x4 __attribute__((ext_vector_type(4)));
typedef unsigned int uint32x2 __attribute__((ext_vector_type(2)));

#define MFMA16(a, b, c) __builtin_amdgcn_mfma_f32_16x16x32_bf16(a, b, c, 0, 0, 0)

// exp(z/8) = exp2(z * log2(e)/8); folded into fkF at projection time.
#define FK_SCALE 0.1803368801111204f  // 0.125 * log2(e)

#define NSPLIT 8

// ---------------------------------------------------------------------------
// MFMA projections (bf16 in / fp32 acc). Grid 512 x 64thr.
//  bx>>8==0: FUSED fk+fv — one field-fragment load feeds BOTH projections
//            (src lane-mapping is identical for the A-role and B-role):
//            fk: C[kout][l] = Wfk(A) . field(B), scaled, +bias -> fkF
//            fv: C[l][v]    = field(A) . Wfv(B), +bias         -> fvF
//  bx>>8==1: hk: C[kout][q] = Wqk(A) . query(B), +bias         -> hkF
// Field is read ONCE (8 MB saved vs split fk/fv blocks).
// ---------------------------------------------------------------------------
__global__ __launch_bounds__(64, 2) void proj_kernel(
    const float* __restrict__ field, const float* __restrict__ query,
    const float* __restrict__ Wfk, const float* __restrict__ bfk,
    const float* __restrict__ Wfv, const float* __restrict__ bfv,
    const float* __restrict__ Wqk, const float* __restrict__ bqk,
    u16* __restrict__ fkF, u16* __restrict__ fvF, u16* __restrict__ hkF) {
  const int lane = threadIdx.x;
  const int q15 = lane & 15, quad = lane >> 4;
  const int bx = blockIdx.x;
  const int fused = (bx >> 8) == 0;   // fk+fv from field, else hk from query
  const int b = (bx >> 6) & 3;
  const int l0 = (bx & 63) * 64;

  const float* src = fused ? field : query;
  const float* sp = src + (size_t)b * (128 * 4096);

  // src frags: B[k=f][n=l] for the W-as-A passes; same regs serve as
  // A[m=l][k=f] for the fv pass (identical lane mapping).
  bf16x8 fr1[4][4];
#pragma unroll
  for (int t = 0; t < 4; ++t)
#pragma unroll
    for (int ks = 0; ks < 4; ++ks) {
      const float* pp = sp + (size_t)(ks * 32 + quad * 8) * 4096 + l0 + t * 16 + q15;
      bf16x8 v;
#pragma unroll
      for (int j = 0; j < 8; ++j) v[j] = (__bf16)pp[(size_t)j * 4096];
      fr1[t][ks] = v;
    }

  auto loadW = [&](const float* W, bf16x8 fr2[4][4]) {
#pragma unroll
    for (int t = 0; t < 4; ++t)
#pragma unroll
      for (int ks = 0; ks < 4; ++ks) {
        const float* pp = W + (size_t)(t * 16 + q15) * 128 + ks * 32 + quad * 8;
        f32x4 w0 = *reinterpret_cast<const f32x4*>(pp);
        f32x4 w1 = *reinterpret_cast<const f32x4*>(pp + 4);
        bf16x8 v;
#pragma unroll
        for (int j = 0; j < 4; ++j) { v[j] = (__bf16)w0[j]; v[4 + j] = (__bf16)w1[j]; }
        fr2[t][ks] = v;
      }
  };

  bf16x8 fr2[4][4];

  // ---- pass 1: W-as-A (fk when fused, hk otherwise) ----
  {
    const float* W    = fused ? Wfk : Wqk;
    const float* bias = fused ? bfk : bqk;
    const float cs    = fused ? FK_SCALE : 1.0f;
    u16* outF         = fused ? fkF : hkF;
    loadW(W, fr2);
#pragma unroll
    for (int nn = 0; nn < 4; ++nn) {
      f32x4 Cn[4];
#pragma unroll
      for (int mm = 0; mm < 4; ++mm) Cn[mm] = (f32x4){0.f, 0.f, 0.f, 0.f};
#pragma unroll
      for (int ks = 0; ks < 4; ++ks)
#pragma unroll
        for (int mm = 0; mm < 4; ++mm)
          Cn[mm] = MFMA16(fr2[mm][ks], fr1[nn][ks], Cn[mm]);
      // C rows = kout = mm*16+quad*4+r, cols = (l or q) = l0+nn*16+q15.
#pragma unroll
      for (int mm = 0; mm < 4; ++mm) {
        f32x4 bz = *reinterpret_cast<const f32x4*>(bias + mm * 16 + quad * 4);
        bf16x4 o;
#pragma unroll
        for (int r = 0; r < 4; ++r) o[r] = (__bf16)((Cn[mm][r] + bz[r]) * cs);
        u16* dst = outF +
            ((size_t)((b * 256 + (l0 >> 4) + nn) * 2) + (mm >> 1)) * 512 +
            (((2 * mm + (quad >> 1)) & 3) * 16 + q15) * 8 + (quad & 1) * 4;
        *reinterpret_cast<uint32x2*>(dst) = __builtin_bit_cast(uint32x2, o);
      }
    }
  }

  // ---- pass 2 (fused only): field-as-A with Wfv-as-B -> fvF ----
  if (fused) {
    loadW(Wfv, fr2);
#pragma unroll
    for (int nn = 0; nn < 4; ++nn) {
      f32x4 Cn[4];
#pragma unroll
      for (int mm = 0; mm < 4; ++mm) Cn[mm] = (f32x4){0.f, 0.f, 0.f, 0.f};
#pragma unroll
      for (int ks = 0; ks < 4; ++ks)
#pragma unroll
        for (int mm = 0; mm < 4; ++mm)
          Cn[mm] = MFMA16(fr1[mm][ks], fr2[nn][ks], Cn[mm]);
      // C rows = l = l0+mm*16+quad*4+r, cols = v = nn*16+q15
      const float bv = bfv[nn * 16 + q15];
#pragma unroll
      for (int mm = 0; mm < 4; ++mm) {
        bf16x4 o;
#pragma unroll
        for (int r = 0; r < 4; ++r) o[r] = (__bf16)(Cn[mm][r] + bv);
        u16* dst = fvF +
            ((size_t)((b * 4 + nn) * 64 + (l0 >> 6)) * 2 + (mm >> 1)) * 512 +
            (((2 * mm + (quad >> 1)) & 3) * 16 + q15) * 8 + (quad & 1) * 4;
        *reinterpret_cast<uint32x2*>(dst) = __builtin_bit_cast(uint32x2, o);
      }
    }
  }
}

// ---------------------------------------------------------------------------
// Attention: barrier-free, cross-chunk pipelined, q-stripe 64 per wave.
// EXACT R9 structure (117.9us best): NSPLIT=8, grid 2048, (64,2) -- the
// accumulator set (~180 live regs) fits 2 waves/SIMD; (64,3) provably
// spills to scratch (R10: 481MB of HBM spill traffic, 2x slowdown).
// Double-buffered 8KB LDS; PV(it-1) overlaps S(it); 1KB contiguous
// fragment loads; XCD-pinned b. Deltas vs R9: Ynum stored bf16;
// s_setprio(1) around MFMA clusters (T5: attn-verified +4-7%).
// UNCHANGED this round (verified at 109.3us).
// ---------------------------------------------------------------------------
__global__ __launch_bounds__(64, 2) void attn_kernel(
    const u16* __restrict__ fkF, const u16* __restrict__ hkF,
    const u16* __restrict__ fvF, u16* __restrict__ Ynum,
    float* __restrict__ den) {
  constexpr int LL = 4096, CH = 64, NITER = (LL / NSPLIT) / CH;  // 8
  const int lane = threadIdx.x;
  const int q15 = lane & 15;
  const int quad = lane >> 4;
  const int id = blockIdx.x;
  const int b = id & 3;
  const int qblk = (id >> 2) & 63;      // 64 q each
  const int split = id >> 8;
  const int l0base = split * (LL / NSPLIT);

  __shared__ __align__(16) char sP[2][8192];  // P[l64][q64] in read-order

  // hk B-frags, persistent; contiguous 1KB loads from hkF
  bf16x8 hkf[4][2];
#pragma unroll
  for (int j = 0; j < 4; ++j)
#pragma unroll
    for (int ks = 0; ks < 2; ++ks)
      hkf[j][ks] = *reinterpret_cast<const bf16x8*>(
          hkF + ((size_t)((b * 256 + qblk * 4 + j) * 2 + ks)) * 512 + lane * 8);

  bf16x8 ones;
#pragma unroll
  for (int j = 0; j < 8; ++j) ones[j] = (__bf16)1.0f;

  f32x4 Yacc[4][4];
#pragma unroll
  for (int mm = 0; mm < 4; ++mm)
#pragma unroll
    for (int nn = 0; nn < 4; ++nn) Yacc[mm][nn] = (f32x4){0.f, 0.f, 0.f, 0.f};
  f32x4 denAcc[4];
#pragma unroll
  for (int nn = 0; nn < 4; ++nn) denAcc[nn] = (f32x4){0.f, 0.f, 0.f, 0.f};

  const int wbase = (quad >> 1) * 256 + q15 * 16 + (quad & 1) * 8;
  const int rbase = lane * 16;

  bf16x8 fkf[4][2];  // A-frags of fk for current chunk (strip s = 16 l)
  bf16x8 af[4][2];   // A-frags of fv for chunk it-1 at PV time

  auto loadFK = [&](int l0) {
    const int t0 = l0 >> 4;
#pragma unroll
    for (int s = 0; s < 4; ++s)
#pragma unroll
      for (int ks = 0; ks < 2; ++ks)
        fkf[s][ks] = *reinterpret_cast<const bf16x8*>(
            fkF + ((size_t)((b * 256 + t0 + s) * 2 + ks)) * 512 + lane * 8);
  };
  auto loadAF = [&](int l0) {
    const int cl = l0 >> 6;
#pragma unroll
    for (int mm = 0; mm < 4; ++mm)
#pragma unroll
      for (int ks = 0; ks < 2; ++ks)
        af[mm][ks] = *reinterpret_cast<const bf16x8*>(
            fvF + ((size_t)(((b * 4 + mm) * 64 + cl) * 2 + ks)) * 512 + lane * 8);
  };
  auto Sphase = [&](char* sPb) {
#pragma unroll
    for (int s = 0; s < 4; ++s) {
      f32x4 accS[4];
#pragma unroll
      for (int jj = 0; jj < 4; ++jj) accS[jj] = (f32x4){0.f, 0.f, 0.f, 0.f};
      __builtin_amdgcn_s_setprio(1);
#pragma unroll
      for (int ks = 0; ks < 2; ++ks)
#pragma unroll
        for (int jj = 0; jj < 4; ++jj)
          accS[jj] = MFMA16(fkf[s][ks], hkf[jj][ks], accS[jj]);
      __builtin_amdgcn_s_setprio(0);
      char* wp = sPb + (s >> 1) * 4096 + (s & 1) * 512 + wbase;
#pragma unroll
      for (int jj = 0; jj < 4; ++jj) {
        bf16x4 pk;
#pragma unroll
        for (int r = 0; r < 4; ++r)
          pk[r] = (__bf16)__builtin_amdgcn_exp2f(accS[jj][r]);
        *reinterpret_cast<uint32x2*>(wp + jj * 1024) =
            __builtin_bit_cast(uint32x2, pk);
      }
    }
  };
  auto PVphase = [&](const char* sPr) {
#pragma unroll
    for (int ks = 0; ks < 2; ++ks) {
      bf16x8 bfr[4];
#pragma unroll
      for (int nn = 0; nn < 4; ++nn)
        bfr[nn] = *reinterpret_cast<const bf16x8*>(
            sPr + ks * 4096 + nn * 1024 + rbase);
      __builtin_amdgcn_s_setprio(1);
#pragma unroll
      for (int nn = 0; nn < 4; ++nn)
        denAcc[nn] = MFMA16(ones, bfr[nn], denAcc[nn]);
#pragma unroll
      for (int mm = 0; mm < 4; ++mm)
#pragma unroll
        for (int nn = 0; nn < 4; ++nn)
          Yacc[mm][nn] = MFMA16(af[mm][ks], bfr[nn], Yacc[mm][nn]);
      __builtin_amdgcn_s_setprio(0);
    }
  };

  // --- prologue ---
  loadFK(l0base);
  loadAF(l0base);
  Sphase(sP[0]);
  loadFK(l0base + CH);

  // --- steady state: PV(it-1) overlaps S(it); loads one chunk ahead ---
#pragma unroll 2
  for (int it = 1; it < NITER; ++it) {
    const int l0 = l0base + it * CH;
    Sphase(sP[it & 1]);
    if (it + 1 < NITER) loadFK(l0 + CH);
    PVphase(sP[(it - 1) & 1]);
    loadAF(l0);
  }
  PVphase(sP[(NITER - 1) & 1]);

  // --- epilogue: bf16 fragment-order Ynum (coalesced 8B) + denom ---
  const size_t slot = ((size_t)split * 4 + b) * 64 + qblk;
  if (quad == 0) {
#pragma unroll
    for (int nn = 0; nn < 4; ++nn)
      den[slot * 64 + nn * 16 + q15] = denAcc[nn][0];  // all C rows equal
  }
  u16* Yo = Ynum + slot * 4096;
#pragma unroll
  for (int mm = 0; mm < 4; ++mm)
#pragma unroll
    for (int nn = 0; nn < 4; ++nn) {
      bf16x4 o;
#pragma unroll
      for (int r = 0; r < 4; ++r) o[r] = (__bf16)Yacc[mm][nn][r];
      *reinterpret_cast<uint32x2*>(Yo + (mm * 4 + nn) * 256 + lane * 4) =
          __builtin_bit_cast(uint32x2, o);
    }
}

// ---------------------------------------------------------------------------
// Combine the NSPLIT l-splits and normalize. out[b][v][q], 1M elements.
// Ynum bf16 fragment order: [slot][mm4][nn4][lane64][r4].
// One thread per r-quad: each split is ONE coalesced 8B load; den amortized
// 4x; single reciprocal per thread (3 fewer IEEE divs).
// ---------------------------------------------------------------------------
__global__ __launch_bounds__(256) void combine_kernel(
    const u16* __restrict__ Yn, const float* __restrict__ dn,
    float* __restrict__ out) {
  const int t = blockIdx.x * 256 + threadIdx.x;  // 262144 threads
  const int q = t & 4095;
  const int vg = (t >> 12) & 15;   // v = vg*4 + r
  const int b = t >> 16;
  const int qb = q >> 6;
  const int mm = vg >> 2, md = vg & 3;
  const int nn = (q >> 4) & 3;
  const int off0 = ((mm * 4 + nn) * 64 + md * 16 + (q & 15)) * 4;
  f32x4 num = {0.f, 0.f, 0.f, 0.f};
  float d = 1e-16f;
#pragma unroll
  for (int s = 0; s < NSPLIT; ++s) {
    const size_t slot = ((size_t)s * 4 + b) * 64 + qb;
    bf16x4 o = __builtin_bit_cast(bf16x4,
        *reinterpret_cast<const uint32x2*>(Yn + slot * 4096 + off0));
#pragma unroll
    for (int r = 0; r < 4; ++r) num[r] += (float)o[r];
    d += dn[slot * 64 + (q & 63)];
  }
  const float inv = 1.0f / d;
  float* op = out + (((size_t)b * 64 + vg * 4) * 4096) + q;
#pragma unroll
  for (int r = 0; r < 4; ++r) op[(size_t)r * 4096] = num[r] * inv;
}

extern "C" void kernel_launch(void* const* d_in, const int* in_sizes, int n_in,
                              void* d_out, int out_size, void* d_ws,
                              size_t ws_size, hipStream_t stream) {
  const float* field = (const float*)d_in[0];
  const float* query = (const float*)d_in[1];
  const float* Wfk = (const float*)d_in[2];
  const float* bfk = (const float*)d_in[3];
  const float* Wfv = (const float*)d_in[4];
  const float* bfv = (const float*)d_in[5];
  const float* Wqk = (const float*)d_in[6];
  const float* bqk = (const float*)d_in[7];
  float* out = (float*)d_out;

  char* ws = (char*)d_ws;
  u16* fkF = (u16*)(ws);                       // 2 MB  A-frag order, scaled
  u16* hkF = (u16*)(ws + (2ull << 20));        // 2 MB  B-frag order
  u16* fvF = (u16*)(ws + (4ull << 20));        // 2 MB  A-frag order
  u16* Ynum = (u16*)(ws + (6ull << 20));       // 16 MB bf16 [2048 slots][4096]
  float* den = (float*)(ws + (22ull << 20));   // 512 KB [2048 slots][64]

  proj_kernel<<<dim3(512), 64, 0, stream>>>(field, query, Wfk, bfk, Wfv, bfv,
                                            Wqk, bqk, fkF, fvF, hkF);
  attn_kernel<<<dim3(2048), 64, 0, stream>>>(fkF, hkF, fvF, Ynum, den);
  combine_kernel<<<dim3(1024), 256, 0, stream>>>(Ynum, den, out);
}

// Round 3
// 107.036 us; speedup vs baseline: 1.0259x; 1.0259x over previous
//
#include <hip/hip_runtime.h>
#include <hip/hip_bf16.h>

typedef unsigned short u16;
typedef __bf16 bf16x8 __attribute__((ext_vector_type(8)));
typedef __bf16 bf16x4 __attribute__((ext_vector_type(4)));
typedef float f32x4 __attribute__((ext_vector_type(4)));
typedef float f32x2 __attribute__((ext_vector_type(2)));
typedef unsigned int uint32x2 __attribute__((ext_vector_type(2)));

#define MFMA16(a, b, c) __builtin_amdgcn_mfma_f32_16x16x32_bf16(a, b, c, 0, 0, 0)

// exp(z/8) = exp2(z * log2(e)/8); folded into fkF at projection time.
#define FK_SCALE 0.1803368801111204f  // 0.125 * log2(e)

#define NSPLIT 8

// ---------------------------------------------------------------------------
// MFMA projections (bf16 in / fp32 acc). UNFUSED, 32-l granularity for max
// parallelism: proj is latency-bound (~22MB traffic = 3.5us roofline but
// 0.5 waves/SIMD in R1/R2). Grid 1536 x 64thr = 6 waves/CU.
// bx>>9: 0=fk, 1=fv, 2=hk;  b=(bx>>7)&3;  l0=(bx&127)*32.
//  fk: C[kout][l] = Wfk(A) . field(B), scaled, +bias -> fkF (A-frag order)
//  fv: C[l][v]    = field(A) . Wfv(B), +bias         -> fvF (A-frag order)
//  hk: C[kout][q] = Wqk(A) . query(B), +bias         -> hkF (B-frag order)
// ---------------------------------------------------------------------------
__global__ __launch_bounds__(64, 2) void proj_kernel(
    const float* __restrict__ field, const float* __restrict__ query,
    const float* __restrict__ Wfk, const float* __restrict__ bfk,
    const float* __restrict__ Wfv, const float* __restrict__ bfv,
    const float* __restrict__ Wqk, const float* __restrict__ bqk,
    u16* __restrict__ fkF, u16* __restrict__ fvF, u16* __restrict__ hkF) {
  const int lane = threadIdx.x;
  const int q15 = lane & 15, quad = lane >> 4;
  const int bx = blockIdx.x;
  const int p = bx >> 9;          // 0=fk, 1=fv, 2=hk
  const int b = (bx >> 7) & 3;
  const int l0 = (bx & 127) * 32;

  const float* src  = (p == 2) ? query : field;
  const float* W    = (p == 0) ? Wfk : (p == 1) ? Wfv : Wqk;
  const float* bias = (p == 0) ? bfk : (p == 1) ? bfv : bqk;
  const float* sp = src + (size_t)b * (128 * 4096);

  // src frags, 2 strips of 16 l: p!=1: B[k=f][n=l]; p==1: A[m=l][k=f]
  // (identical lane mapping).
  bf16x8 fr1[2][4];
#pragma unroll
  for (int t = 0; t < 2; ++t)
#pragma unroll
    for (int ks = 0; ks < 4; ++ks) {
      const float* pp = sp + (size_t)(ks * 32 + quad * 8) * 4096 + l0 + t * 16 + q15;
      bf16x8 v;
#pragma unroll
      for (int j = 0; j < 8; ++j) v[j] = (__bf16)pp[(size_t)j * 4096];
      fr1[t][ks] = v;
    }

  // W frags (full 128x128): p!=1: A[m=kout][k=f]; p==1: B[k=f][n=v].
  bf16x8 fr2[4][4];
#pragma unroll
  for (int t = 0; t < 4; ++t)
#pragma unroll
    for (int ks = 0; ks < 4; ++ks) {
      const float* pp = W + (size_t)(t * 16 + q15) * 128 + ks * 32 + quad * 8;
      f32x4 w0 = *reinterpret_cast<const f32x4*>(pp);
      f32x4 w1 = *reinterpret_cast<const f32x4*>(pp + 4);
      bf16x8 v;
#pragma unroll
      for (int j = 0; j < 4; ++j) { v[j] = (__bf16)w0[j]; v[4 + j] = (__bf16)w1[j]; }
      fr2[t][ks] = v;
    }

  if (p == 1) {
    // fv: m-tiles = 2 l-strips, n-tiles = 4 (v). Strip index within the
    // 64-l fvF chunk: s = mm + 2*(c32&1).
    const int sb = (l0 >> 4) & 2;
#pragma unroll
    for (int nn = 0; nn < 4; ++nn) {
      f32x4 Cn[2];
#pragma unroll
      for (int mm = 0; mm < 2; ++mm) Cn[mm] = (f32x4){0.f, 0.f, 0.f, 0.f};
#pragma unroll
      for (int ks = 0; ks < 4; ++ks)
#pragma unroll
        for (int mm = 0; mm < 2; ++mm)
          Cn[mm] = MFMA16(fr1[mm][ks], fr2[nn][ks], Cn[mm]);
      const float bv = bias[nn * 16 + q15];
#pragma unroll
      for (int mm = 0; mm < 2; ++mm) {
        const int s = mm + sb;
        bf16x4 o;
#pragma unroll
        for (int r = 0; r < 4; ++r) o[r] = (__bf16)(Cn[mm][r] + bv);
        u16* dst = fvF +
            ((size_t)((b * 4 + nn) * 64 + (l0 >> 6)) * 2 + (s >> 1)) * 512 +
            (((2 * s + (quad >> 1)) & 3) * 16 + q15) * 8 + (quad & 1) * 4;
        *reinterpret_cast<uint32x2*>(dst) = __builtin_bit_cast(uint32x2, o);
      }
    }
  } else {
    // fk/hk: m-tiles = 4 (kout), n-tiles = 2 l-strips.
    const float cs = (p == 0) ? FK_SCALE : 1.0f;
    u16* outF = (p == 0) ? fkF : hkF;
#pragma unroll
    for (int nn = 0; nn < 2; ++nn) {
      f32x4 Cn[4];
#pragma unroll
      for (int mm = 0; mm < 4; ++mm) Cn[mm] = (f32x4){0.f, 0.f, 0.f, 0.f};
#pragma unroll
      for (int ks = 0; ks < 4; ++ks)
#pragma unroll
        for (int mm = 0; mm < 4; ++mm)
          Cn[mm] = MFMA16(fr2[mm][ks], fr1[nn][ks], Cn[mm]);
      // C rows = kout = mm*16+quad*4+r, cols = (l or q) = l0+nn*16+q15.
#pragma unroll
      for (int mm = 0; mm < 4; ++mm) {
        f32x4 bz = *reinterpret_cast<const f32x4*>(bias + mm * 16 + quad * 4);
        bf16x4 o;
#pragma unroll
        for (int r = 0; r < 4; ++r) o[r] = (__bf16)((Cn[mm][r] + bz[r]) * cs);
        u16* dst = outF +
            ((size_t)((b * 256 + (l0 >> 4) + nn) * 2) + (mm >> 1)) * 512 +
            (((2 * mm + (quad >> 1)) & 3) * 16 + q15) * 8 + (quad & 1) * 4;
        *reinterpret_cast<uint32x2*>(dst) = __builtin_bit_cast(uint32x2, o);
      }
    }
  }
}

// ---------------------------------------------------------------------------
// Attention: barrier-free, cross-chunk pipelined, q-stripe 64 per wave.
// EXACT R9 structure (117.9us best): NSPLIT=8, grid 2048, (64,2) -- the
// accumulator set (~180 live regs) fits 2 waves/SIMD; (64,3) provably
// spills to scratch (R10: 481MB of HBM spill traffic, 2x slowdown).
// Double-buffered 8KB LDS; PV(it-1) overlaps S(it); 1KB contiguous
// fragment loads; XCD-pinned b. Deltas vs R9: Ynum stored bf16;
// s_setprio(1) around MFMA clusters (T5: attn-verified +4-7%).
// UNCHANGED (verified at 109.3us).
// ---------------------------------------------------------------------------
__global__ __launch_bounds__(64, 2) void attn_kernel(
    const u16* __restrict__ fkF, const u16* __restrict__ hkF,
    const u16* __restrict__ fvF, u16* __restrict__ Ynum,
    float* __restrict__ den) {
  constexpr int LL = 4096, CH = 64, NITER = (LL / NSPLIT) / CH;  // 8
  const int lane = threadIdx.x;
  const int q15 = lane & 15;
  const int quad = lane >> 4;
  const int id = blockIdx.x;
  const int b = id & 3;
  const int qblk = (id >> 2) & 63;      // 64 q each
  const int split = id >> 8;
  const int l0base = split * (LL / NSPLIT);

  __shared__ __align__(16) char sP[2][8192];  // P[l64][q64] in read-order

  // hk B-frags, persistent; contiguous 1KB loads from hkF
  bf16x8 hkf[4][2];
#pragma unroll
  for (int j = 0; j < 4; ++j)
#pragma unroll
    for (int ks = 0; ks < 2; ++ks)
      hkf[j][ks] = *reinterpret_cast<const bf16x8*>(
          hkF + ((size_t)((b * 256 + qblk * 4 + j) * 2 + ks)) * 512 + lane * 8);

  bf16x8 ones;
#pragma unroll
  for (int j = 0; j < 8; ++j) ones[j] = (__bf16)1.0f;

  f32x4 Yacc[4][4];
#pragma unroll
  for (int mm = 0; mm < 4; ++mm)
#pragma unroll
    for (int nn = 0; nn < 4; ++nn) Yacc[mm][nn] = (f32x4){0.f, 0.f, 0.f, 0.f};
  f32x4 denAcc[4];
#pragma unroll
  for (int nn = 0; nn < 4; ++nn) denAcc[nn] = (f32x4){0.f, 0.f, 0.f, 0.f};

  const int wbase = (quad >> 1) * 256 + q15 * 16 + (quad & 1) * 8;
  const int rbase = lane * 16;

  bf16x8 fkf[4][2];  // A-frags of fk for current chunk (strip s = 16 l)
  bf16x8 af[4][2];   // A-frags of fv for chunk it-1 at PV time

  auto loadFK = [&](int l0) {
    const int t0 = l0 >> 4;
#pragma unroll
    for (int s = 0; s < 4; ++s)
#pragma unroll
      for (int ks = 0; ks < 2; ++ks)
        fkf[s][ks] = *reinterpret_cast<const bf16x8*>(
            fkF + ((size_t)((b * 256 + t0 + s) * 2 + ks)) * 512 + lane * 8);
  };
  auto loadAF = [&](int l0) {
    const int cl = l0 >> 6;
#pragma unroll
    for (int mm = 0; mm < 4; ++mm)
#pragma unroll
      for (int ks = 0; ks < 2; ++ks)
        af[mm][ks] = *reinterpret_cast<const bf16x8*>(
            fvF + ((size_t)(((b * 4 + mm) * 64 + cl) * 2 + ks)) * 512 + lane * 8);
  };
  auto Sphase = [&](char* sPb) {
#pragma unroll
    for (int s = 0; s < 4; ++s) {
      f32x4 accS[4];
#pragma unroll
      for (int jj = 0; jj < 4; ++jj) accS[jj] = (f32x4){0.f, 0.f, 0.f, 0.f};
      __builtin_amdgcn_s_setprio(1);
#pragma unroll
      for (int ks = 0; ks < 2; ++ks)
#pragma unroll
        for (int jj = 0; jj < 4; ++jj)
          accS[jj] = MFMA16(fkf[s][ks], hkf[jj][ks], accS[jj]);
      __builtin_amdgcn_s_setprio(0);
      char* wp = sPb + (s >> 1) * 4096 + (s & 1) * 512 + wbase;
#pragma unroll
      for (int jj = 0; jj < 4; ++jj) {
        bf16x4 pk;
#pragma unroll
        for (int r = 0; r < 4; ++r)
          pk[r] = (__bf16)__builtin_amdgcn_exp2f(accS[jj][r]);
        *reinterpret_cast<uint32x2*>(wp + jj * 1024) =
            __builtin_bit_cast(uint32x2, pk);
      }
    }
  };
  auto PVphase = [&](const char* sPr) {
#pragma unroll
    for (int ks = 0; ks < 2; ++ks) {
      bf16x8 bfr[4];
#pragma unroll
      for (int nn = 0; nn < 4; ++nn)
        bfr[nn] = *reinterpret_cast<const bf16x8*>(
            sPr + ks * 4096 + nn * 1024 + rbase);
      __builtin_amdgcn_s_setprio(1);
#pragma unroll
      for (int nn = 0; nn < 4; ++nn)
        denAcc[nn] = MFMA16(ones, bfr[nn], denAcc[nn]);
#pragma unroll
      for (int mm = 0; mm < 4; ++mm)
#pragma unroll
        for (int nn = 0; nn < 4; ++nn)
          Yacc[mm][nn] = MFMA16(af[mm][ks], bfr[nn], Yacc[mm][nn]);
      __builtin_amdgcn_s_setprio(0);
    }
  };

  // --- prologue ---
  loadFK(l0base);
  loadAF(l0base);
  Sphase(sP[0]);
  loadFK(l0base + CH);

  // --- steady state: PV(it-1) overlaps S(it); loads one chunk ahead ---
#pragma unroll 2
  for (int it = 1; it < NITER; ++it) {
    const int l0 = l0base + it * CH;
    Sphase(sP[it & 1]);
    if (it + 1 < NITER) loadFK(l0 + CH);
    PVphase(sP[(it - 1) & 1]);
    loadAF(l0);
  }
  PVphase(sP[(NITER - 1) & 1]);

  // --- epilogue: bf16 fragment-order Ynum (coalesced 8B) + denom ---
  const size_t slot = ((size_t)split * 4 + b) * 64 + qblk;
  if (quad == 0) {
#pragma unroll
    for (int nn = 0; nn < 4; ++nn)
      den[slot * 64 + nn * 16 + q15] = denAcc[nn][0];  // all C rows equal
  }
  u16* Yo = Ynum + slot * 4096;
#pragma unroll
  for (int mm = 0; mm < 4; ++mm)
#pragma unroll
    for (int nn = 0; nn < 4; ++nn) {
      bf16x4 o;
#pragma unroll
      for (int r = 0; r < 4; ++r) o[r] = (__bf16)Yacc[mm][nn][r];
      *reinterpret_cast<uint32x2*>(Yo + (mm * 4 + nn) * 256 + lane * 4) =
          __builtin_bit_cast(uint32x2, o);
    }
}

// ---------------------------------------------------------------------------
// Combine the NSPLIT l-splits and normalize. out[b][v][q], 1M elements.
// Ynum bf16 fragment order: [slot][mm4][nn4][lane64][r4].
// One thread per (r-quad x q-pair): each split is ONE 16B bf16x8 load
// (the coalescing sweet spot) covering r0..3 of q and q+1; den is one
// float2; outputs are float2 stores. 131072 threads.
// ---------------------------------------------------------------------------
__global__ __launch_bounds__(256) void combine_kernel(
    const u16* __restrict__ Yn, const float* __restrict__ dn,
    float* __restrict__ out) {
  const int t = blockIdx.x * 256 + threadIdx.x;  // 131072 threads
  const int qh = t & 2047;
  const int q = qh * 2;            // even q; thread covers q, q+1
  const int vg = (t >> 11) & 15;   // v = vg*4 + r
  const int b = t >> 15;
  const int qb = q >> 6;
  const int mm = vg >> 2, md = vg & 3;
  const int nn = (q >> 4) & 3;
  const int off0 = ((mm * 4 + nn) * 64 + md * 16 + (q & 15)) * 4;  // 16B-aligned
  f32x4 n0 = {0.f, 0.f, 0.f, 0.f}, n1 = {0.f, 0.f, 0.f, 0.f};
  float d0 = 1e-16f, d1 = 1e-16f;
#pragma unroll
  for (int s = 0; s < NSPLIT; ++s) {
    const size_t slot = ((size_t)s * 4 + b) * 64 + qb;
    bf16x8 o = *reinterpret_cast<const bf16x8*>(Yn + slot * 4096 + off0);
#pragma unroll
    for (int r = 0; r < 4; ++r) { n0[r] += (float)o[r]; n1[r] += (float)o[4 + r]; }
    f32x2 dd = *reinterpret_cast<const f32x2*>(dn + slot * 64 + (q & 63));
    d0 += dd[0]; d1 += dd[1];
  }
  const float inv0 = 1.0f / d0, inv1 = 1.0f / d1;
  float* op = out + (((size_t)b * 64 + vg * 4) * 4096) + q;
#pragma unroll
  for (int r = 0; r < 4; ++r) {
    f32x2 w = {n0[r] * inv0, n1[r] * inv1};
    *reinterpret_cast<f32x2*>(op + (size_t)r * 4096) = w;
  }
}

extern "C" void kernel_launch(void* const* d_in, const int* in_sizes, int n_in,
                              void* d_out, int out_size, void* d_ws,
                              size_t ws_size, hipStream_t stream) {
  const float* field = (const float*)d_in[0];
  const float* query = (const float*)d_in[1];
  const float* Wfk = (const float*)d_in[2];
  const float* bfk = (const float*)d_in[3];
  const float* Wfv = (const float*)d_in[4];
  const float* bfv = (const float*)d_in[5];
  const float* Wqk = (const float*)d_in[6];
  const float* bqk = (const float*)d_in[7];
  float* out = (float*)d_out;

  char* ws = (char*)d_ws;
  u16* fkF = (u16*)(ws);                       // 2 MB  A-frag order, scaled
  u16* hkF = (u16*)(ws + (2ull << 20));        // 2 MB  B-frag order
  u16* fvF = (u16*)(ws + (4ull << 20));        // 2 MB  A-frag order
  u16* Ynum = (u16*)(ws + (6ull << 20));       // 16 MB bf16 [2048 slots][4096]
  float* den = (float*)(ws + (22ull << 20));   // 512 KB [2048 slots][64]

  proj_kernel<<<dim3(1536), 64, 0, stream>>>(field, query, Wfk, bfk, Wfv, bfv,
                                             Wqk, bqk, fkF, fvF, hkF);
  attn_kernel<<<dim3(2048), 64, 0, stream>>>(fkF, hkF, fvF, Ynum, den);
  combine_kernel<<<dim3(512), 256, 0, stream>>>(Ynum, den, out);
}